// Round 2
// baseline (4135.041 us; speedup 1.0000x reference)
//
#include <hip/hip_runtime.h>

// UNetDecoderBlock: sparse 2x upsample (8x 128->64 GEMM) + hash skip-add +
// 3x submanifold 3^3 conv (64->64) with BN(batch-stats)+LeakyReLU, residual.
// Fixed problem: NX=40000, NS=200000, M=320000, S_out=128.
//
// Round 1 (resubmit; prior round was a GPU-acquisition infra failure):
//   fp32 everywhere, output-stationary gather-conv.
//   conv: 64 rows/block, LDS-staged transposed f-tile, 16 rows/thread register
//   tile, per-lane coalesced weight streaming. BN stats fused into conv
//   epilogue (atomicAdd), BN+lrelu applied during next conv's staging.

#define S2 128
#define TABN (S2 * S2 * S2)

// ---------------- skip-coord hash scatter ----------------
__global__ void k_scatter_skip(const int* __restrict__ sc, int* __restrict__ table_s, int NS) {
    int i = blockIdx.x * 256 + threadIdx.x;
    if (i >= NS) return;
    int x = sc[i * 3], y = sc[i * 3 + 1], z = sc[i * 3 + 2];
    table_s[(x * S2 + y) * S2 + z] = i;
}

// ---------------- upsample + skip-add + table_o scatter ----------------
// feats[8n+o][c] = sum_d x[n][d] * w_up[7-o][d][c]  (+ skip_feats on hash hit)
// block: 256 threads = 4 row-groups x 64 channels; 16 parents per block.
__global__ __launch_bounds__(256) void k_upsample(
    const float* __restrict__ x, const float* __restrict__ wup,
    const int* __restrict__ cords, const float* __restrict__ skipf,
    const int* __restrict__ table_s, int* __restrict__ table_o,
    float* __restrict__ feats, int NX) {
    __shared__ float xl[16][132];  // [parent][d], pad to dodge write conflicts
    int tid = threadIdx.x;
    int P0 = blockIdx.x * 16;
    {   // stage 16 parent rows (16x128 fp32 = 8KB), coalesced float4 loads
        int p = tid >> 4, d0 = (tid & 15) * 8;
        const float* src = x + (size_t)(P0 + p) * 128 + d0;
        float4 a = *(const float4*)src;
        float4 b = *(const float4*)(src + 4);
        xl[p][d0 + 0] = a.x; xl[p][d0 + 1] = a.y; xl[p][d0 + 2] = a.z; xl[p][d0 + 3] = a.w;
        xl[p][d0 + 4] = b.x; xl[p][d0 + 5] = b.y; xl[p][d0 + 6] = b.z; xl[p][d0 + 7] = b.w;
    }
    __syncthreads();
    int c = tid & 63, g = tid >> 6;   // g uniform per wave
    float acc[8][4];
#pragma unroll
    for (int o = 0; o < 8; ++o)
#pragma unroll
        for (int p = 0; p < 4; ++p) acc[o][p] = 0.f;
    for (int d = 0; d < 128; ++d) {
        float xv0 = xl[g * 4 + 0][d], xv1 = xl[g * 4 + 1][d];
        float xv2 = xl[g * 4 + 2][d], xv3 = xl[g * 4 + 3][d];
#pragma unroll
        for (int o = 0; o < 8; ++o) {
            float wv = wup[(size_t)(7 - o) * 8192 + d * 64 + c];  // coalesced over c
            acc[o][0] += xv0 * wv; acc[o][1] += xv1 * wv;
            acc[o][2] += xv2 * wv; acc[o][3] += xv3 * wv;
        }
    }
    for (int p = 0; p < 4; ++p) {
        int parent = P0 + g * 4 + p;
        int cx = cords[parent * 3], cy = cords[parent * 3 + 1], cz = cords[parent * 3 + 2];
#pragma unroll
        for (int o = 0; o < 8; ++o) {
            int X = 2 * cx + (o >> 2), Y = 2 * cy + ((o >> 1) & 1), Z = 2 * cz + (o & 1);
            int lin = (X * S2 + Y) * S2 + Z;
            int m = parent * 8 + o;
            int j = table_s[lin];                 // wave-uniform addr -> broadcast
            float v = acc[o][p];
            if (j >= 0) v += skipf[(size_t)j * 64 + c];
            feats[(size_t)m * 64 + c] = v;        // coalesced
            if (c == 0) table_o[lin] = m;
        }
    }
}

// ---------------- neighbor table (27 x M) ----------------
__global__ void k_build_nbr(const int* __restrict__ cords, const int* __restrict__ table_o,
                            int* __restrict__ nbr, int M) {
    int m = blockIdx.x * 256 + threadIdx.x;
    if (m >= M) return;
    int n = m >> 3, o = m & 7;
    int X = 2 * cords[n * 3] + (o >> 2);
    int Y = 2 * cords[n * 3 + 1] + ((o >> 1) & 1);
    int Z = 2 * cords[n * 3 + 2] + (o & 1);
#pragma unroll
    for (int kk = 0; kk < 27; ++kk) {
        int nx = X + kk / 9 - 1, ny = Y + (kk / 3) % 3 - 1, nz = Z + kk % 3 - 1;
        int idx = -1;
        if ((unsigned)nx < (unsigned)S2 && (unsigned)ny < (unsigned)S2 && (unsigned)nz < (unsigned)S2)
            idx = table_o[(nx * S2 + ny) * S2 + nz];
        nbr[(size_t)kk * M + m] = idx;
    }
}

// ---------------- submanifold conv (+ fused input BN/lrelu, + stats) ----------------
// z[m][c] = sum_k sum_d xf(fin[nbr[k][m]][d]) * W[k][d][c]
// block: 64 rows, 256 threads (4 waves x 64 ch), 16 rows per thread.
template <bool XF>
__global__ __launch_bounds__(256) void k_subconv(
    const float* __restrict__ fin, const float* __restrict__ W,
    const int* __restrict__ nbr, float* __restrict__ zout,
    float* __restrict__ stats, const float* __restrict__ coef,
    float slope, int M) {
    __shared__ float fl[64 * 68];  // fl[d][row], pad 68 (16B-aligned rows)
    __shared__ int lidx[64];
    int tid = threadIdx.x;
    int c = tid & 63, g = tid >> 6;  // g uniform per wave
    int r0 = blockIdx.x * 64;
    float scale = 1.f, shift = 0.f;
    if (XF) { scale = coef[c]; shift = coef[64 + c]; }
    float acc[16];
#pragma unroll
    for (int j = 0; j < 16; ++j) acc[j] = 0.f;

    for (int k = 0; k < 27; ++k) {
        __syncthreads();
        if (tid < 64) lidx[tid] = nbr[(size_t)k * M + r0 + tid];
        __syncthreads();
        // stage 64 gathered rows into LDS (transposed), BN+lrelu on the fly
#pragma unroll
        for (int it = 0; it < 16; ++it) {
            int row = it * 4 + g;
            int idx = lidx[row];
            float v = 0.f;
            if (idx >= 0) {
                v = fin[(size_t)idx * 64 + c];  // coalesced 256B gather
                if (XF) { float t = v * scale + shift; v = fmaxf(t, slope * t); }
            }
            fl[c * 68 + row] = v;
        }
        __syncthreads();
#pragma unroll
        for (int d = 0; d < 64; ++d) {
            float wv = W[((size_t)k * 64 + d) * 64 + c];  // coalesced, L1-resident
            const float4* fp = (const float4*)&fl[d * 68 + g * 16];  // broadcast reads
            float4 a0 = fp[0], a1 = fp[1], a2 = fp[2], a3 = fp[3];
            acc[0] += a0.x * wv;  acc[1] += a0.y * wv;  acc[2] += a0.z * wv;  acc[3] += a0.w * wv;
            acc[4] += a1.x * wv;  acc[5] += a1.y * wv;  acc[6] += a1.z * wv;  acc[7] += a1.w * wv;
            acc[8] += a2.x * wv;  acc[9] += a2.y * wv;  acc[10] += a2.z * wv; acc[11] += a2.w * wv;
            acc[12] += a3.x * wv; acc[13] += a3.y * wv; acc[14] += a3.z * wv; acc[15] += a3.w * wv;
        }
    }
#pragma unroll
    for (int j = 0; j < 16; ++j)
        zout[(size_t)(r0 + g * 16 + j) * 64 + c] = acc[j];
    // fused BN batch-stats: per-channel sum / sumsq
    float s = 0.f, s2 = 0.f;
#pragma unroll
    for (int j = 0; j < 16; ++j) { s += acc[j]; s2 += acc[j] * acc[j]; }
    __syncthreads();
    fl[g * 64 + c] = s;
    fl[256 + g * 64 + c] = s2;
    __syncthreads();
    if (g == 0) {
        float ts = fl[c] + fl[64 + c] + fl[128 + c] + fl[192 + c];
        float t2 = fl[256 + c] + fl[320 + c] + fl[384 + c] + fl[448 + c];
        atomicAdd(&stats[c], ts);
        atomicAdd(&stats[64 + c], t2);
    }
}

// ---------------- BN coefficient finalize ----------------
__global__ void k_finalize(const float* __restrict__ stats, const float* __restrict__ g,
                           const float* __restrict__ b, float* __restrict__ coef, float invM) {
    int c = threadIdx.x;
    if (c >= 64) return;
    float mu = stats[c] * invM;
    float var = stats[64 + c] * invM - mu * mu;
    float sc = g[c] * rsqrtf(var + 1e-4f);
    coef[c] = sc;
    coef[64 + c] = b[c] - mu * sc;
}

// ---------------- residual epilogue: lrelu(bn3(z3) + lrelu(bn1(z1)), 0.333) ----------------
__global__ void k_final(const float* __restrict__ z3, const float* __restrict__ z1,
                        const float* __restrict__ coef1, const float* __restrict__ coef3,
                        float* __restrict__ out, int n4) {
    int t = blockIdx.x * 256 + threadIdx.x;
    if (t >= n4) return;
    int cb = (t * 4) & 63;
    float4 v3 = ((const float4*)z3)[t];
    float4 v1 = ((const float4*)z1)[t];
    float a3[4] = {v3.x, v3.y, v3.z, v3.w};
    float a1[4] = {v1.x, v1.y, v1.z, v1.w};
    float r[4];
#pragma unroll
    for (int j = 0; j < 4; ++j) {
        int cc = cb + j;
        float x1 = a1[j] * coef1[cc] + coef1[64 + cc];
        x1 = fmaxf(x1, 0.05f * x1);
        float x3 = a3[j] * coef3[cc] + coef3[64 + cc];
        float rr = x3 + x1;
        r[j] = fmaxf(rr, 0.333f * rr);
    }
    ((float4*)out)[t] = make_float4(r[0], r[1], r[2], r[3]);
}

extern "C" void kernel_launch(void* const* d_in, const int* in_sizes, int n_in,
                              void* d_out, int out_size, void* d_ws, size_t ws_size,
                              hipStream_t stream) {
    const float* x_feats    = (const float*)d_in[0];
    const float* skip_feats = (const float*)d_in[1];
    const float* w_up       = (const float*)d_in[2];
    const float* w1         = (const float*)d_in[3];
    const float* w2         = (const float*)d_in[4];
    const float* w3         = (const float*)d_in[5];
    const float* g1 = (const float*)d_in[6],  *b1 = (const float*)d_in[7];
    const float* g2 = (const float*)d_in[8],  *b2 = (const float*)d_in[9];
    const float* g3 = (const float*)d_in[10], *b3 = (const float*)d_in[11];
    const int* cords      = (const int*)d_in[12];
    const int* skip_cords = (const int*)d_in[13];
    int NX = in_sizes[12] / 3;
    int NS = in_sizes[13] / 3;
    int M = NX * 8;

    char* ws = (char*)d_ws;
    size_t off = 0;
    auto alloc = [&](size_t bytes) -> char* {
        char* p = ws + off;
        off += (bytes + 255) & ~(size_t)255;
        return p;
    };
    int*   table_s = (int*)alloc((size_t)TABN * 4);
    int*   table_o = (int*)alloc((size_t)TABN * 4);
    int*   nbr     = (int*)alloc((size_t)27 * M * 4);
    float* A       = (float*)alloc((size_t)M * 64 * 4);  // feats, later z3
    float* B       = (float*)alloc((size_t)M * 64 * 4);  // z1
    float* C       = (float*)alloc((size_t)M * 64 * 4);  // z2
    float* stats   = (float*)alloc(384 * 4);             // 3 x [sum64 | sumsq64]
    float* coefs   = (float*)alloc(384 * 4);             // 3 x [scale64 | shift64]

    hipMemsetAsync(table_s, 0xFF, (size_t)TABN * 4, stream);  // -1
    hipMemsetAsync(table_o, 0xFF, (size_t)TABN * 4, stream);  // -1
    hipMemsetAsync(stats, 0, 384 * 4, stream);

    float invM = 1.f / (float)M;
    k_scatter_skip<<<(NS + 255) / 256, 256, 0, stream>>>(skip_cords, table_s, NS);
    k_upsample<<<NX / 16, 256, 0, stream>>>(x_feats, w_up, cords, skip_feats,
                                            table_s, table_o, A, NX);
    k_build_nbr<<<(M + 255) / 256, 256, 0, stream>>>(cords, table_o, nbr, M);

    k_subconv<false><<<M / 64, 256, 0, stream>>>(A, w1, nbr, B, stats, nullptr, 0.f, M);
    k_finalize<<<1, 64, 0, stream>>>(stats, g1, b1, coefs, invM);
    k_subconv<true><<<M / 64, 256, 0, stream>>>(B, w2, nbr, C, stats + 128, coefs, 0.05f, M);
    k_finalize<<<1, 64, 0, stream>>>(stats + 128, g2, b2, coefs + 128, invM);
    k_subconv<true><<<M / 64, 256, 0, stream>>>(C, w3, nbr, A, stats + 256, coefs + 128, 0.05f, M);
    k_finalize<<<1, 64, 0, stream>>>(stats + 256, g3, b3, coefs + 256, invM);

    k_final<<<(M * 16 + 255) / 256, 256, 0, stream>>>(A, B, coefs, coefs + 256,
                                                      (float*)d_out, M * 16);
}

// Round 3
// 1369.603 us; speedup vs baseline: 3.0192x; 3.0192x over previous
//
#include <hip/hip_runtime.h>

// UNetDecoderBlock: sparse 2x upsample + hash skip-add + 3x submanifold 3^3
// conv (64->64, BN batch-stats + LeakyReLU) + residual.
// NX=40000, M=320000, S_out=128.
//
// Round 3: bf16 MFMA gather-conv, zero LDS in the conv hot loop.
//  - activations stored bf16; A-fragments gathered straight from global
//    (lane l: row=l&15 of the wave's 16-row tile, 16B = 8 consecutive ch).
//  - weights pre-packed into MFMA B-fragment lane order -> coalesced loads.
//  - BN+lrelu hoisted out of the 27x gather into one k_xform pass per layer.
//  - BN stats from fp32 accumulators via shfl reduce + atomicAdd.

#define S2 128
#define TABN (S2 * S2 * S2)

typedef __attribute__((ext_vector_type(8))) short short8;
typedef __attribute__((ext_vector_type(4))) float f32x4;

__device__ inline float b2f(unsigned short u) {
    return __uint_as_float(((unsigned)u) << 16);
}
__device__ inline unsigned short f2b(float f) {   // RNE
    unsigned u = __float_as_uint(f);
    return (unsigned short)((u + 0x7FFF + ((u >> 16) & 1)) >> 16);
}

// ---------------- skip-coord hash scatter ----------------
__global__ void k_scatter_skip(const int* __restrict__ sc, int* __restrict__ table_s, int NS) {
    int i = blockIdx.x * 256 + threadIdx.x;
    if (i >= NS) return;
    table_s[(sc[i * 3] * S2 + sc[i * 3 + 1]) * S2 + sc[i * 3 + 2]] = i;
}

// ---------------- weight pack: fp32 [27][64][64] -> bf16 MFMA B-frag order --
// out[t], t = k*4096 + ks*2048 + nt*512 + lane*8 + j
// element = W[k][ d = ks*32 + (lane>>4)*8 + j ][ c = nt*16 + (lane&15) ]
__global__ void k_packw(const float* __restrict__ w, unsigned short* __restrict__ wpk) {
    int t = blockIdx.x * 256 + threadIdx.x;
    if (t >= 27 * 4096) return;
    int j = t & 7, l = (t >> 3) & 63, nt = (t >> 9) & 3, ks = (t >> 11) & 1, k = t >> 12;
    int d = ks * 32 + (l >> 4) * 8 + j;
    int c = nt * 16 + (l & 15);
    wpk[t] = f2b(w[(k * 64 + d) * 64 + c]);
}

// ---------------- upsample + skip-add + table_o scatter (fp32 math, bf16 out)
__global__ __launch_bounds__(256) void k_upsample(
    const float* __restrict__ x, const float* __restrict__ wup,
    const int* __restrict__ cords, const float* __restrict__ skipf,
    const int* __restrict__ table_s, int* __restrict__ table_o,
    unsigned short* __restrict__ feats, int NX) {
    __shared__ float xl[16][132];
    int tid = threadIdx.x;
    int P0 = blockIdx.x * 16;
    {
        int p = tid >> 4, d0 = (tid & 15) * 8;
        const float* src = x + (size_t)(P0 + p) * 128 + d0;
        float4 a = *(const float4*)src;
        float4 b = *(const float4*)(src + 4);
        xl[p][d0 + 0] = a.x; xl[p][d0 + 1] = a.y; xl[p][d0 + 2] = a.z; xl[p][d0 + 3] = a.w;
        xl[p][d0 + 4] = b.x; xl[p][d0 + 5] = b.y; xl[p][d0 + 6] = b.z; xl[p][d0 + 7] = b.w;
    }
    __syncthreads();
    int c = tid & 63, g = tid >> 6;
    float acc[8][4];
#pragma unroll
    for (int o = 0; o < 8; ++o)
#pragma unroll
        for (int p = 0; p < 4; ++p) acc[o][p] = 0.f;
    for (int d = 0; d < 128; ++d) {
        float xv0 = xl[g * 4 + 0][d], xv1 = xl[g * 4 + 1][d];
        float xv2 = xl[g * 4 + 2][d], xv3 = xl[g * 4 + 3][d];
#pragma unroll
        for (int o = 0; o < 8; ++o) {
            float wv = wup[(size_t)(7 - o) * 8192 + d * 64 + c];
            acc[o][0] += xv0 * wv; acc[o][1] += xv1 * wv;
            acc[o][2] += xv2 * wv; acc[o][3] += xv3 * wv;
        }
    }
    for (int p = 0; p < 4; ++p) {
        int parent = P0 + g * 4 + p;
        int cx = cords[parent * 3], cy = cords[parent * 3 + 1], cz = cords[parent * 3 + 2];
#pragma unroll
        for (int o = 0; o < 8; ++o) {
            int X = 2 * cx + (o >> 2), Y = 2 * cy + ((o >> 1) & 1), Z = 2 * cz + (o & 1);
            int lin = (X * S2 + Y) * S2 + Z;
            int m = parent * 8 + o;
            int j = table_s[lin];
            float v = acc[o][p];
            if (j >= 0) v += skipf[(size_t)j * 64 + c];
            feats[(size_t)m * 64 + c] = f2b(v);
            if (c == 0) table_o[lin] = m;
        }
    }
}

// ---------------- neighbor table (27 x M) ----------------
__global__ void k_build_nbr(const int* __restrict__ cords, const int* __restrict__ table_o,
                            int* __restrict__ nbr, int M) {
    int m = blockIdx.x * 256 + threadIdx.x;
    if (m >= M) return;
    int n = m >> 3, o = m & 7;
    int X = 2 * cords[n * 3] + (o >> 2);
    int Y = 2 * cords[n * 3 + 1] + ((o >> 1) & 1);
    int Z = 2 * cords[n * 3 + 2] + (o & 1);
#pragma unroll
    for (int kk = 0; kk < 27; ++kk) {
        int nx = X + kk / 9 - 1, ny = Y + (kk / 3) % 3 - 1, nz = Z + kk % 3 - 1;
        int idx = -1;
        if ((unsigned)nx < (unsigned)S2 && (unsigned)ny < (unsigned)S2 && (unsigned)nz < (unsigned)S2)
            idx = table_o[(nx * S2 + ny) * S2 + nz];
        nbr[(size_t)kk * M + m] = idx;
    }
}

// ---------------- MFMA gather-conv ----------------
// block: 256 threads = 4 waves; wave owns 32 rows x 64 cols.
// Per k: A-frags gathered from global (bf16), B-frags from packed weights.
__global__ __launch_bounds__(256) void k_conv_mfma(
    const unsigned short* __restrict__ fin, const unsigned short* __restrict__ wpk,
    const int* __restrict__ nbr, unsigned short* __restrict__ zout,
    float* __restrict__ stats, int M) {
    int tid = threadIdx.x;
    int lane = tid & 63, wv = tid >> 6;
    int l15 = lane & 15, kg = lane >> 4;
    int rbase = blockIdx.x * 128 + wv * 32;

    f32x4 acc[2][4];
#pragma unroll
    for (int m = 0; m < 2; ++m)
#pragma unroll
        for (int nt = 0; nt < 4; ++nt) acc[m][nt] = (f32x4){0.f, 0.f, 0.f, 0.f};

    const short8 kzero = {0, 0, 0, 0, 0, 0, 0, 0};
    for (int k = 0; k < 27; ++k) {
        const int* nrow = nbr + (size_t)k * M + rbase;
        int i0 = nrow[l15];
        int i1 = nrow[16 + l15];
        const unsigned short* p0 = fin + (size_t)(i0 < 0 ? 0 : i0) * 64 + kg * 8;
        const unsigned short* p1 = fin + (size_t)(i1 < 0 ? 0 : i1) * 64 + kg * 8;
        short8 a00 = *(const short8*)p0;
        short8 a01 = *(const short8*)(p0 + 32);
        short8 a10 = *(const short8*)p1;
        short8 a11 = *(const short8*)(p1 + 32);
        if (i0 < 0) { a00 = kzero; a01 = kzero; }
        if (i1 < 0) { a10 = kzero; a11 = kzero; }
        const unsigned short* wb = wpk + (size_t)k * 4096 + lane * 8;
#pragma unroll
        for (int nt = 0; nt < 4; ++nt) {
            short8 b0 = *(const short8*)(wb + nt * 512);
            short8 b1 = *(const short8*)(wb + 2048 + nt * 512);
            acc[0][nt] = __builtin_amdgcn_mfma_f32_16x16x32_bf16(a00, b0, acc[0][nt], 0, 0, 0);
            acc[0][nt] = __builtin_amdgcn_mfma_f32_16x16x32_bf16(a01, b1, acc[0][nt], 0, 0, 0);
            acc[1][nt] = __builtin_amdgcn_mfma_f32_16x16x32_bf16(a10, b0, acc[1][nt], 0, 0, 0);
            acc[1][nt] = __builtin_amdgcn_mfma_f32_16x16x32_bf16(a11, b1, acc[1][nt], 0, 0, 0);
        }
    }

    // epilogue: bf16 store + BN batch-stats (fp32 accumulators)
    float s[4] = {0.f, 0.f, 0.f, 0.f}, q[4] = {0.f, 0.f, 0.f, 0.f};
#pragma unroll
    for (int m = 0; m < 2; ++m)
#pragma unroll
        for (int nt = 0; nt < 4; ++nt)
#pragma unroll
            for (int j = 0; j < 4; ++j) {
                float v = acc[m][nt][j];
                int row = rbase + m * 16 + kg * 4 + j;
                zout[(size_t)row * 64 + nt * 16 + l15] = f2b(v);
                s[nt] += v; q[nt] += v * v;
            }
#pragma unroll
    for (int nt = 0; nt < 4; ++nt) {
        float ss = s[nt], qq = q[nt];
        ss += __shfl_xor(ss, 16); ss += __shfl_xor(ss, 32);
        qq += __shfl_xor(qq, 16); qq += __shfl_xor(qq, 32);
        if (kg == 0) {
            atomicAdd(&stats[nt * 16 + l15], ss);
            atomicAdd(&stats[64 + nt * 16 + l15], qq);
        }
    }
}

// ---------------- BN coefficient finalize ----------------
__global__ void k_finalize(const float* __restrict__ stats, const float* __restrict__ g,
                           const float* __restrict__ b, float* __restrict__ coef, float invM) {
    int c = threadIdx.x;
    if (c >= 64) return;
    float mu = stats[c] * invM;
    float var = stats[64 + c] * invM - mu * mu;
    float sc = g[c] * rsqrtf(var + 1e-4f);
    coef[c] = sc;
    coef[64 + c] = b[c] - mu * sc;
}

// ---------------- elementwise BN+lrelu(0.05), in place, bf16 ----------------
__global__ void k_xform(unsigned short* __restrict__ z, const float* __restrict__ coef, int n8) {
    int t = blockIdx.x * 256 + threadIdx.x;
    if (t >= n8) return;
    short8 v = ((const short8*)z)[t];
    int cb = (t * 8) & 63;
    short8 r;
#pragma unroll
    for (int j = 0; j < 8; ++j) {
        float f = b2f((unsigned short)v[j]) * coef[cb + j] + coef[64 + cb + j];
        f = fmaxf(f, 0.05f * f);
        r[j] = (short)f2b(f);
    }
    ((short8*)z)[t] = r;
}

// ---------------- residual epilogue: lrelu(bn3(z3) + x1, 0.333) -> fp32 -----
__global__ void k_final(const unsigned short* __restrict__ z3,
                        const unsigned short* __restrict__ x1,
                        const float* __restrict__ coef3, float* __restrict__ out, int n8) {
    int t = blockIdx.x * 256 + threadIdx.x;
    if (t >= n8) return;
    short8 v3 = ((const short8*)z3)[t];
    short8 v1 = ((const short8*)x1)[t];
    int cb = (t * 8) & 63;
    float4 o0, o1;
    float rr[8];
#pragma unroll
    for (int j = 0; j < 8; ++j) {
        float f3 = b2f((unsigned short)v3[j]) * coef3[cb + j] + coef3[64 + cb + j];
        float r = f3 + b2f((unsigned short)v1[j]);
        rr[j] = fmaxf(r, 0.333f * r);
    }
    o0 = make_float4(rr[0], rr[1], rr[2], rr[3]);
    o1 = make_float4(rr[4], rr[5], rr[6], rr[7]);
    ((float4*)out)[t * 2] = o0;
    ((float4*)out)[t * 2 + 1] = o1;
}

extern "C" void kernel_launch(void* const* d_in, const int* in_sizes, int n_in,
                              void* d_out, int out_size, void* d_ws, size_t ws_size,
                              hipStream_t stream) {
    const float* x_feats    = (const float*)d_in[0];
    const float* skip_feats = (const float*)d_in[1];
    const float* w_up       = (const float*)d_in[2];
    const float* w1         = (const float*)d_in[3];
    const float* w2         = (const float*)d_in[4];
    const float* w3         = (const float*)d_in[5];
    const float* g1 = (const float*)d_in[6],  *b1 = (const float*)d_in[7];
    const float* g2 = (const float*)d_in[8],  *b2 = (const float*)d_in[9];
    const float* g3 = (const float*)d_in[10], *b3 = (const float*)d_in[11];
    const int* cords      = (const int*)d_in[12];
    const int* skip_cords = (const int*)d_in[13];
    int NX = in_sizes[12] / 3;
    int NS = in_sizes[13] / 3;
    int M = NX * 8;

    char* ws = (char*)d_ws;
    size_t off = 0;
    auto alloc = [&](size_t bytes) -> char* {
        char* p = ws + off;
        off += (bytes + 255) & ~(size_t)255;
        return p;
    };
    int* table_s = (int*)alloc((size_t)TABN * 4);
    int* table_o = (int*)alloc((size_t)TABN * 4);
    int* nbr     = (int*)alloc((size_t)27 * M * 4);
    unsigned short* A = (unsigned short*)alloc((size_t)M * 64 * 2);  // feats -> z3
    unsigned short* B = (unsigned short*)alloc((size_t)M * 64 * 2);  // z1 -> x1
    unsigned short* C = (unsigned short*)alloc((size_t)M * 64 * 2);  // z2 -> x2
    unsigned short* wp1 = (unsigned short*)alloc(27 * 4096 * 2);
    unsigned short* wp2 = (unsigned short*)alloc(27 * 4096 * 2);
    unsigned short* wp3 = (unsigned short*)alloc(27 * 4096 * 2);
    float* stats = (float*)alloc(384 * 4);
    float* coefs = (float*)alloc(384 * 4);

    hipMemsetAsync(table_s, 0xFF, (size_t)TABN * 4, stream);
    hipMemsetAsync(table_o, 0xFF, (size_t)TABN * 4, stream);
    hipMemsetAsync(stats, 0, 384 * 4, stream);

    float invM = 1.f / (float)M;
    int n8 = M * 64 / 8;

    k_scatter_skip<<<(NS + 255) / 256, 256, 0, stream>>>(skip_cords, table_s, NS);
    k_packw<<<432, 256, 0, stream>>>(w1, wp1);
    k_packw<<<432, 256, 0, stream>>>(w2, wp2);
    k_packw<<<432, 256, 0, stream>>>(w3, wp3);
    k_upsample<<<NX / 16, 256, 0, stream>>>(x_feats, w_up, cords, skip_feats,
                                            table_s, table_o, A, NX);
    k_build_nbr<<<(M + 255) / 256, 256, 0, stream>>>(cords, table_o, nbr, M);

    k_conv_mfma<<<M / 128, 256, 0, stream>>>(A, wp1, nbr, B, stats, M);
    k_finalize<<<1, 64, 0, stream>>>(stats, g1, b1, coefs, invM);
    k_xform<<<(n8 + 255) / 256, 256, 0, stream>>>(B, coefs, n8);          // B := x1

    k_conv_mfma<<<M / 128, 256, 0, stream>>>(B, wp2, nbr, C, stats + 128, M);
    k_finalize<<<1, 64, 0, stream>>>(stats + 128, g2, b2, coefs + 128, invM);
    k_xform<<<(n8 + 255) / 256, 256, 0, stream>>>(C, coefs + 128, n8);    // C := x2

    k_conv_mfma<<<M / 128, 256, 0, stream>>>(C, wp3, nbr, A, stats + 256, M);
    k_finalize<<<1, 64, 0, stream>>>(stats + 256, g3, b3, coefs + 256, invM);

    k_final<<<(n8 + 255) / 256, 256, 0, stream>>>(A, B, coefs + 256, (float*)d_out, n8);
}

// Round 4
// 1104.564 us; speedup vs baseline: 3.7436x; 1.2399x over previous
//
#include <hip/hip_runtime.h>

// UNetDecoderBlock: sparse 2x upsample + hash skip-add + 3x submanifold 3^3
// conv (64->64, BN batch-stats + LeakyReLU) + residual.
// NX=40000, M=320000, S_out=128.
//
// Round 4: latency-bound conv fix.
//  - nbr indices staged in LDS per block (removes HBM hop from gather chain)
//  - invalid neighbors -> guard row M (zeros); no masks/selects in hot loop
//  - 2-deep register double-buffer pipeline (A gathers + B frags), explicit
//    2-step unroll; 64 rows/wave (halves weight L2 re-read traffic)

#define S2 128
#define TABN (S2 * S2 * S2)

typedef __attribute__((ext_vector_type(8))) short short8;
typedef __attribute__((ext_vector_type(4))) float f32x4;

__device__ inline float b2f(unsigned short u) {
    return __uint_as_float(((unsigned)u) << 16);
}
__device__ inline unsigned short f2b(float f) {   // RNE
    unsigned u = __float_as_uint(f);
    return (unsigned short)((u + 0x7FFF + ((u >> 16) & 1)) >> 16);
}

// ---------------- skip-coord hash scatter ----------------
__global__ void k_scatter_skip(const int* __restrict__ sc, int* __restrict__ table_s, int NS) {
    int i = blockIdx.x * 256 + threadIdx.x;
    if (i >= NS) return;
    table_s[(sc[i * 3] * S2 + sc[i * 3 + 1]) * S2 + sc[i * 3 + 2]] = i;
}

// ---------------- weight pack: fp32 [27][64][64] -> bf16 MFMA B-frag order --
// out[t], t = k*4096 + ks*2048 + nt*512 + lane*8 + j
// element = W[k][ d = ks*32 + (lane>>4)*8 + j ][ c = nt*16 + (lane&15) ]
__global__ void k_packw(const float* __restrict__ w, unsigned short* __restrict__ wpk) {
    int t = blockIdx.x * 256 + threadIdx.x;
    if (t >= 27 * 4096) return;
    int j = t & 7, l = (t >> 3) & 63, nt = (t >> 9) & 3, ks = (t >> 11) & 1, k = t >> 12;
    int d = ks * 32 + (l >> 4) * 8 + j;
    int c = nt * 16 + (l & 15);
    wpk[t] = f2b(w[(k * 64 + d) * 64 + c]);
}

// ---------------- upsample + skip-add + table_o scatter (fp32 math, bf16 out)
__global__ __launch_bounds__(256) void k_upsample(
    const float* __restrict__ x, const float* __restrict__ wup,
    const int* __restrict__ cords, const float* __restrict__ skipf,
    const int* __restrict__ table_s, int* __restrict__ table_o,
    unsigned short* __restrict__ feats, int NX) {
    __shared__ float xl[16][132];
    int tid = threadIdx.x;
    int P0 = blockIdx.x * 16;
    {
        int p = tid >> 4, d0 = (tid & 15) * 8;
        const float* src = x + (size_t)(P0 + p) * 128 + d0;
        float4 a = *(const float4*)src;
        float4 b = *(const float4*)(src + 4);
        xl[p][d0 + 0] = a.x; xl[p][d0 + 1] = a.y; xl[p][d0 + 2] = a.z; xl[p][d0 + 3] = a.w;
        xl[p][d0 + 4] = b.x; xl[p][d0 + 5] = b.y; xl[p][d0 + 6] = b.z; xl[p][d0 + 7] = b.w;
    }
    __syncthreads();
    int c = tid & 63, g = tid >> 6;
    float acc[8][4];
#pragma unroll
    for (int o = 0; o < 8; ++o)
#pragma unroll
        for (int p = 0; p < 4; ++p) acc[o][p] = 0.f;
    for (int d = 0; d < 128; ++d) {
        float xv0 = xl[g * 4 + 0][d], xv1 = xl[g * 4 + 1][d];
        float xv2 = xl[g * 4 + 2][d], xv3 = xl[g * 4 + 3][d];
#pragma unroll
        for (int o = 0; o < 8; ++o) {
            float wv = wup[(size_t)(7 - o) * 8192 + d * 64 + c];
            acc[o][0] += xv0 * wv; acc[o][1] += xv1 * wv;
            acc[o][2] += xv2 * wv; acc[o][3] += xv3 * wv;
        }
    }
    for (int p = 0; p < 4; ++p) {
        int parent = P0 + g * 4 + p;
        int cx = cords[parent * 3], cy = cords[parent * 3 + 1], cz = cords[parent * 3 + 2];
#pragma unroll
        for (int o = 0; o < 8; ++o) {
            int X = 2 * cx + (o >> 2), Y = 2 * cy + ((o >> 1) & 1), Z = 2 * cz + (o & 1);
            int lin = (X * S2 + Y) * S2 + Z;
            int m = parent * 8 + o;
            int j = table_s[lin];
            float v = acc[o][p];
            if (j >= 0) v += skipf[(size_t)j * 64 + c];
            feats[(size_t)m * 64 + c] = f2b(v);
            if (c == 0) table_o[lin] = m;
        }
    }
}

// ---------------- neighbor table (27 x M); invalid -> M (guard row) --------
__global__ void k_build_nbr(const int* __restrict__ cords, const int* __restrict__ table_o,
                            int* __restrict__ nbr, int M) {
    int m = blockIdx.x * 256 + threadIdx.x;
    if (m >= M) return;
    int n = m >> 3, o = m & 7;
    int X = 2 * cords[n * 3] + (o >> 2);
    int Y = 2 * cords[n * 3 + 1] + ((o >> 1) & 1);
    int Z = 2 * cords[n * 3 + 2] + (o & 1);
#pragma unroll
    for (int kk = 0; kk < 27; ++kk) {
        int nx = X + kk / 9 - 1, ny = Y + (kk / 3) % 3 - 1, nz = Z + kk % 3 - 1;
        int idx = -1;
        if ((unsigned)nx < (unsigned)S2 && (unsigned)ny < (unsigned)S2 && (unsigned)nz < (unsigned)S2)
            idx = table_o[(nx * S2 + ny) * S2 + nz];
        nbr[(size_t)kk * M + m] = (idx < 0) ? M : idx;   // guard row on invalid
    }
}

// ---------------- MFMA gather-conv, pipelined ----------------
// block: 256 threads = 4 waves; wave owns 64 rows x 64 cols (acc[4][4]).
__global__ __launch_bounds__(256, 2) void k_conv_mfma(
    const unsigned short* __restrict__ fin, const unsigned short* __restrict__ wpk,
    const int* __restrict__ nbr, unsigned short* __restrict__ zout,
    float* __restrict__ stats, int M) {
    __shared__ int idx_lds[27 * 256];
    int tid = threadIdx.x;
    int lane = tid & 63, wv = tid >> 6;
    int l15 = lane & 15, kg = lane >> 4;
    int rblk = blockIdx.x * 256;
    int rw = wv * 64;

    {   // stage the block's 27x256 neighbor indices (coalesced int4)
        int col = (tid & 63) * 4;
        for (int q = tid >> 6; q < 27; q += 4) {
            int4 v = *(const int4*)(nbr + (size_t)q * M + rblk + col);
            *(int4*)&idx_lds[q * 256 + col] = v;
        }
    }
    __syncthreads();

    f32x4 acc[4][4];
#pragma unroll
    for (int m = 0; m < 4; ++m)
#pragma unroll
        for (int nt = 0; nt < 4; ++nt) acc[m][nt] = (f32x4){0.f, 0.f, 0.f, 0.f};

    short8 A0[4][2], A1[4][2], B0[8], B1[8];

    auto loadA = [&](short8 A[4][2], int k) {
#pragma unroll
        for (int m = 0; m < 4; ++m) {
            int idx = idx_lds[k * 256 + rw + m * 16 + l15];
            const unsigned short* p = fin + (size_t)idx * 64 + kg * 8;
            A[m][0] = *(const short8*)p;
            A[m][1] = *(const short8*)(p + 32);
        }
    };
    auto loadB = [&](short8 B[8], int k) {
        const unsigned short* wb = wpk + (size_t)k * 4096 + lane * 8;
#pragma unroll
        for (int ks = 0; ks < 2; ++ks)
#pragma unroll
            for (int nt = 0; nt < 4; ++nt)
                B[ks * 4 + nt] = *(const short8*)(wb + ks * 2048 + nt * 512);
    };
    auto domfma = [&](short8 A[4][2], short8 B[8]) {
#pragma unroll
        for (int m = 0; m < 4; ++m)
#pragma unroll
            for (int nt = 0; nt < 4; ++nt) {
                acc[m][nt] = __builtin_amdgcn_mfma_f32_16x16x32_bf16(A[m][0], B[nt], acc[m][nt], 0, 0, 0);
                acc[m][nt] = __builtin_amdgcn_mfma_f32_16x16x32_bf16(A[m][1], B[4 + nt], acc[m][nt], 0, 0, 0);
            }
    };

    loadA(A0, 0); loadB(B0, 0);
    for (int k = 0; k < 26; k += 2) {
        loadA(A1, k + 1); loadB(B1, k + 1);
        domfma(A0, B0);
        loadA(A0, k + 2); loadB(B0, k + 2);
        domfma(A1, B1);
    }
    domfma(A0, B0);   // k = 26

    // epilogue: bf16 store + BN batch-stats
    float s[4] = {0.f, 0.f, 0.f, 0.f}, q[4] = {0.f, 0.f, 0.f, 0.f};
#pragma unroll
    for (int m = 0; m < 4; ++m)
#pragma unroll
        for (int nt = 0; nt < 4; ++nt)
#pragma unroll
            for (int j = 0; j < 4; ++j) {
                float v = acc[m][nt][j];
                int row = rblk + rw + m * 16 + kg * 4 + j;
                zout[(size_t)row * 64 + nt * 16 + l15] = f2b(v);
                s[nt] += v; q[nt] += v * v;
            }
#pragma unroll
    for (int nt = 0; nt < 4; ++nt) {
        float ss = s[nt], qq = q[nt];
        ss += __shfl_xor(ss, 16); ss += __shfl_xor(ss, 32);
        qq += __shfl_xor(qq, 16); qq += __shfl_xor(qq, 32);
        if (kg == 0) {
            atomicAdd(&stats[nt * 16 + l15], ss);
            atomicAdd(&stats[64 + nt * 16 + l15], qq);
        }
    }
}

// ---------------- BN coefficient finalize ----------------
__global__ void k_finalize(const float* __restrict__ stats, const float* __restrict__ g,
                           const float* __restrict__ b, float* __restrict__ coef, float invM) {
    int c = threadIdx.x;
    if (c >= 64) return;
    float mu = stats[c] * invM;
    float var = stats[64 + c] * invM - mu * mu;
    float sc = g[c] * rsqrtf(var + 1e-4f);
    coef[c] = sc;
    coef[64 + c] = b[c] - mu * sc;
}

// ---------------- elementwise BN+lrelu(0.05), in place, bf16 ----------------
__global__ void k_xform(unsigned short* __restrict__ z, const float* __restrict__ coef, int n8) {
    int t = blockIdx.x * 256 + threadIdx.x;
    if (t >= n8) return;
    short8 v = ((const short8*)z)[t];
    int cb = (t * 8) & 63;
    short8 r;
#pragma unroll
    for (int j = 0; j < 8; ++j) {
        float f = b2f((unsigned short)v[j]) * coef[cb + j] + coef[64 + cb + j];
        f = fmaxf(f, 0.05f * f);
        r[j] = (short)f2b(f);
    }
    ((short8*)z)[t] = r;
}

// ---------------- residual epilogue: lrelu(bn3(z3) + x1, 0.333) -> fp32 -----
__global__ void k_final(const unsigned short* __restrict__ z3,
                        const unsigned short* __restrict__ x1,
                        const float* __restrict__ coef3, float* __restrict__ out, int n8) {
    int t = blockIdx.x * 256 + threadIdx.x;
    if (t >= n8) return;
    short8 v3 = ((const short8*)z3)[t];
    short8 v1 = ((const short8*)x1)[t];
    int cb = (t * 8) & 63;
    float rr[8];
#pragma unroll
    for (int j = 0; j < 8; ++j) {
        float f3 = b2f((unsigned short)v3[j]) * coef3[cb + j] + coef3[64 + cb + j];
        float r = f3 + b2f((unsigned short)v1[j]);
        rr[j] = fmaxf(r, 0.333f * r);
    }
    ((float4*)out)[t * 2] = make_float4(rr[0], rr[1], rr[2], rr[3]);
    ((float4*)out)[t * 2 + 1] = make_float4(rr[4], rr[5], rr[6], rr[7]);
}

extern "C" void kernel_launch(void* const* d_in, const int* in_sizes, int n_in,
                              void* d_out, int out_size, void* d_ws, size_t ws_size,
                              hipStream_t stream) {
    const float* x_feats    = (const float*)d_in[0];
    const float* skip_feats = (const float*)d_in[1];
    const float* w_up       = (const float*)d_in[2];
    const float* w1         = (const float*)d_in[3];
    const float* w2         = (const float*)d_in[4];
    const float* w3         = (const float*)d_in[5];
    const float* g1 = (const float*)d_in[6],  *b1 = (const float*)d_in[7];
    const float* g2 = (const float*)d_in[8],  *b2 = (const float*)d_in[9];
    const float* g3 = (const float*)d_in[10], *b3 = (const float*)d_in[11];
    const int* cords      = (const int*)d_in[12];
    const int* skip_cords = (const int*)d_in[13];
    int NX = in_sizes[12] / 3;
    int NS = in_sizes[13] / 3;
    int M = NX * 8;

    char* ws = (char*)d_ws;
    size_t off = 0;
    auto alloc = [&](size_t bytes) -> char* {
        char* p = ws + off;
        off += (bytes + 255) & ~(size_t)255;
        return p;
    };
    int* table_s = (int*)alloc((size_t)TABN * 4);
    int* table_o = (int*)alloc((size_t)TABN * 4);
    int* nbr     = (int*)alloc((size_t)27 * M * 4);
    unsigned short* A = (unsigned short*)alloc((size_t)(M + 1) * 64 * 2);  // feats -> z3
    unsigned short* B = (unsigned short*)alloc((size_t)(M + 1) * 64 * 2);  // z1 -> x1
    unsigned short* C = (unsigned short*)alloc((size_t)(M + 1) * 64 * 2);  // z2 -> x2
    unsigned short* wp1 = (unsigned short*)alloc(27 * 4096 * 2);
    unsigned short* wp2 = (unsigned short*)alloc(27 * 4096 * 2);
    unsigned short* wp3 = (unsigned short*)alloc(27 * 4096 * 2);
    float* stats = (float*)alloc(384 * 4);
    float* coefs = (float*)alloc(384 * 4);

    hipMemsetAsync(table_s, 0xFF, (size_t)TABN * 4, stream);
    hipMemsetAsync(table_o, 0xFF, (size_t)TABN * 4, stream);
    hipMemsetAsync(stats, 0, 384 * 4, stream);
    // zero guard rows (row M) of all activation buffers
    hipMemsetAsync(A + (size_t)M * 64, 0, 128, stream);
    hipMemsetAsync(B + (size_t)M * 64, 0, 128, stream);
    hipMemsetAsync(C + (size_t)M * 64, 0, 128, stream);

    float invM = 1.f / (float)M;
    int n8 = M * 64 / 8;

    k_scatter_skip<<<(NS + 255) / 256, 256, 0, stream>>>(skip_cords, table_s, NS);
    k_packw<<<432, 256, 0, stream>>>(w1, wp1);
    k_packw<<<432, 256, 0, stream>>>(w2, wp2);
    k_packw<<<432, 256, 0, stream>>>(w3, wp3);
    k_upsample<<<NX / 16, 256, 0, stream>>>(x_feats, w_up, cords, skip_feats,
                                            table_s, table_o, A, NX);
    k_build_nbr<<<(M + 255) / 256, 256, 0, stream>>>(cords, table_o, nbr, M);

    k_conv_mfma<<<M / 256, 256, 0, stream>>>(A, wp1, nbr, B, stats, M);
    k_finalize<<<1, 64, 0, stream>>>(stats, g1, b1, coefs, invM);
    k_xform<<<(n8 + 255) / 256, 256, 0, stream>>>(B, coefs, n8);          // B := x1

    k_conv_mfma<<<M / 256, 256, 0, stream>>>(B, wp2, nbr, C, stats + 128, M);
    k_finalize<<<1, 64, 0, stream>>>(stats + 128, g2, b2, coefs + 128, invM);
    k_xform<<<(n8 + 255) / 256, 256, 0, stream>>>(C, coefs + 128, n8);    // C := x2

    k_conv_mfma<<<M / 256, 256, 0, stream>>>(C, wp3, nbr, A, stats + 256, M);
    k_finalize<<<1, 64, 0, stream>>>(stats + 256, g3, b3, coefs + 256, invM);

    k_final<<<(n8 + 255) / 256, 256, 0, stream>>>(A, B, coefs + 256, (float*)d_out, n8);
}